// Round 8
// baseline (187.036 us; speedup 1.0000x reference)
//
#include <hip/hip_runtime.h>
#include <hip/hip_bf16.h>
#include <math.h>

#define M_ROWS 16384
#define DIM 1024

typedef __attribute__((ext_vector_type(8))) short short8;
typedef __attribute__((ext_vector_type(4))) float f32x4;

#define MFMA_BF16(a, b, c) __builtin_amdgcn_mfma_f32_16x16x32_bf16(a, b, c, 0, 0, 0)

#define GLOAD16(gp, lp) __builtin_amdgcn_global_load_lds( \
    (const __attribute__((address_space(1))) unsigned int*)(gp), \
    (__attribute__((address_space(3))) unsigned int*)(lp), 16, 0, 0)

__device__ __forceinline__ short bf16_hi(float x) {
    return (short)__bfloat16_as_ushort(__float2bfloat16(x));
}
__device__ __forceinline__ float bf16_f(short s) {
    return __bfloat162float(__ushort_as_bfloat16((unsigned short)s));
}

__device__ __forceinline__ float fast_asinh(float x) {
    float ax = fabsf(x);
    float r = __logf(ax + sqrtf(fmaf(ax, ax, 1.0f)));
    return copysignf(r, x);
}
__device__ __forceinline__ float fast_sinh(float x) {
    float e = __expf(x), em = __expf(-x);
    return 0.5f * (e - em);
}

__device__ __forceinline__ float waveReduceSum(float v) {
#pragma unroll
    for (int off = 32; off > 0; off >>= 1) v += __shfl_down(v, off, 64);
    return v;
}

// ---- column norms of weigh_v (axis=0) ----
__global__ void colnorm_partial(const float* __restrict__ W, float* __restrict__ part) {
    int col = (blockIdx.x & 3) * 256 + threadIdx.x;
    int r0 = (blockIdx.x >> 2) * 128;
    float s = 0.f;
#pragma unroll 8
    for (int i = 0; i < 128; ++i) {
        float t = W[(size_t)(r0 + i) * DIM + col];
        s += t * t;
    }
    part[(size_t)(blockIdx.x >> 2) * DIM + col] = s;
}

__global__ void colnorm_final(const float* __restrict__ part, float* __restrict__ invn) {
    int col = blockIdx.x * 256 + threadIdx.x;
    float s = 0.f;
#pragma unroll
    for (int p = 0; p < 8; ++p) s += part[(size_t)p * DIM + col];
    float n = fminf(fmaxf(sqrtf(s), 1e-6f), 1e6f);
    invn[col] = 1.0f / n;
}

// ---- transpose + bf16 hi/lo split of weigh_v into interleaved layout ----
// Bws[n][kb][0..31]=hi shorts, [32..63]=lo shorts  (row stride 2048 shorts)
__global__ __launch_bounds__(256) void wsplit(const float* __restrict__ W,
                                              short* __restrict__ Bws) {
    __shared__ float tile[64][65];
    const int t = threadIdx.x;
    const int k0 = (blockIdx.x >> 4) * 64, n0 = (blockIdx.x & 15) * 64;
    const int rk = t >> 4;          // 0..15
    const int cn = (t & 15) * 4;    // 0..60
#pragma unroll
    for (int p = 0; p < 4; ++p) {
        float4 v = *(const float4*)&W[(size_t)(k0 + rk + p * 16) * DIM + n0 + cn];
        tile[rk + p * 16][cn + 0] = v.x;
        tile[rk + p * 16][cn + 1] = v.y;
        tile[rk + p * 16][cn + 2] = v.z;
        tile[rk + p * 16][cn + 3] = v.w;
    }
    __syncthreads();
    const int rn = t >> 4;
    const int ck = (t & 15) * 4;          // 0..60, 4 k within one 32-chunk
    const int kbl = (t & 15) >> 3;        // 0 or 1
    const int ko = (t & 7) * 4;           // ck & 31
#pragma unroll
    for (int p = 0; p < 4; ++p) {
        int n = rn + p * 16;
        union { short s[4]; uint2 u; } ph, pl;
#pragma unroll
        for (int e = 0; e < 4; ++e) {
            float a = tile[ck + e][n];
            short h = bf16_hi(a);
            ph.s[e] = h;
            pl.s[e] = bf16_hi(a - bf16_f(h));
        }
        size_t base = (size_t)(n0 + n) * 2048 + (size_t)(k0 >> 5) * 64 + kbl * 64;
        *(uint2*)&Bws[base + ko]      = ph.u;
        *(uint2*)&Bws[base + 32 + ko] = pl.u;
    }
}

// ---- per-row prep into interleaved layout: Aws[row][kb][hi32|lo32] ----
__global__ __launch_bounds__(256) void rowprep_split(
    const float* __restrict__ in, const float* __restrict__ cptr,
    short* __restrict__ Aws, float* __restrict__ cx2) {
    const int row = blockIdx.x, t = threadIdx.x;
    float4 v = ((const float4*)(in + (size_t)row * DIM))[t];
    float s = v.x * v.x + v.y * v.y + v.z * v.z + v.w * v.w;
    s = waveReduceSum(s);
    __shared__ float red[4];
    __shared__ float rsv_sh;
    int wid = t >> 6, lane = t & 63;
    if (lane == 0) red[wid] = s;
    __syncthreads();
    if (t == 0) {
        float stot = red[0] + red[1] + red[2] + red[3];
        float cc = cptr[0], rc = sqrtf(cc);
        float un = sqrtf(fmaxf(stot, 1e-15f));          // _safe_norm(u)
        float xs = tanhf(rc * un) / (rc * un);          // x = xs*u
        float xn = sqrtf(fmaxf(xs * xs * stot, 1e-15f));
        float mn = (1.0f - 1e-5f) / rc;
        float pf = (xn > mn) ? (mn / xn) : 1.0f;        // proj
        float rsv = rc * xs * pf;                       // rcx = rsv*u
        rsv_sh = rsv;
        cx2[row] = rsv * rsv * stot;
    }
    __syncthreads();
    float rsv = rsv_sh;
    float a[4] = {v.x * rsv, v.y * rsv, v.z * rsv, v.w * rsv};
    union { short s[4]; uint2 u; } ph, pl;
#pragma unroll
    for (int e = 0; e < 4; ++e) {
        short h = bf16_hi(a[e]);
        ph.s[e] = h;
        pl.s[e] = bf16_hi(a[e] - bf16_f(h));
    }
    const int kb = t >> 3;          // (t*4)>>5
    const int ko = (t & 7) * 4;
    size_t base = (size_t)row * 2048 + kb * 64;
    *(uint2*)&Aws[base + ko]      = ph.u;
    *(uint2*)&Aws[base + 32 + ko] = pl.u;
}

// ---- MFMA GEMM (bf16x3), 256x128 tile, 8 waves (4x2 of 64x64), BK=32 ----
// 3-buffer LDS ring, counted vmcnt(6), 4-phase fine interleave per K-step
// (m201/T3 structure): each phase = {ds_read subtile, stage issue, barrier,
// lgkmcnt(0), setprio(1), 12 MFMA, setprio(0), barrier}.
// LDS rows: [rows][8 slots of 16B] (slots 0-3 hi, 4-7 lo), slot ^= row&7.
__global__ __launch_bounds__(512, 2) void gemm_mfma(
    const short* __restrict__ Aws, const short* __restrict__ Bws,
    const float* __restrict__ cx2, const float* __restrict__ invn,
    const float* __restrict__ wg, const float* __restrict__ bias,
    const float* __restrict__ cptr, float* __restrict__ Y) {
    __shared__ char smem[147456];   // 3 units x (A 32 KB + B 16 KB)

    // 512 wgs = 64 by x 8 bx; XCD-chunked swizzle (512 % 8 == 0, bijective)
    const int j = blockIdx.x;
    const int wgid = (j & 7) * 64 + (j >> 3);
    const int by = wgid >> 3, bx = wgid & 7;
    const int row0 = by * 256, col0 = bx * 128;

    const int t = threadIdx.x;              // 0..511
    const int l = t & 63, w = t >> 6;       // 8 waves
    const int wr = (w >> 1) * 64, wc = (w & 1) * 64;
    const int fr = l & 15, fk3 = l >> 4;

    // staging: thread t -> row t>>3 of each 64-row chunk, lds slot t&7
    const int row_t = t >> 3;
    const int slotA = ((t & 7) ^ (row_t & 7)) * 8;      // pre-swizzled source slot
    const size_t gA0 = (size_t)(row0 + row_t) * 2048 + slotA;
    const size_t gB0 = (size_t)(col0 + row_t) * 2048 + slotA;

    // 6 loads per K-step: A = 4x64 rows, B = 2x64 rows (prologue form)
#define STAGE(u, s) do { \
        short* dA_ = (short*)(smem + (u) * 49152); \
        short* dB_ = dA_ + 16384; \
        const int kbo_ = (s) * 64; \
        GLOAD16(Aws + gA0 + kbo_,          dA_ + t * 8); \
        GLOAD16(Aws + gA0 + 131072 + kbo_, dA_ + 4096 + t * 8); \
        GLOAD16(Aws + gA0 + 262144 + kbo_, dA_ + 8192 + t * 8); \
        GLOAD16(Aws + gA0 + 393216 + kbo_, dA_ + 12288 + t * 8); \
        GLOAD16(Bws + gB0 + kbo_,          dB_ + t * 8); \
        GLOAD16(Bws + gB0 + 131072 + kbo_, dB_ + 4096 + t * 8); \
    } while (0)

    f32x4 acc[4][4] = {};

    // prologue: stage steps 0,1; wait step 0 (oldest 6), keep 6 in flight
    STAGE(0, 0);
    STAGE(1, 1);
    asm volatile("s_waitcnt vmcnt(6)" ::: "memory");
    __builtin_amdgcn_s_barrier();

    // one phase: A-row-group i vs all B frags (12 MFMA), m201 grain
#define PHASE(i, S0, S1) do { \
        int r_ = wr + (i) * 16 + fr; \
        int rb_ = r_ * 64, rx_ = r_ & 7; \
        short8 ah_ = *(const short8*)&sA[rb_ + ((fk3 ^ rx_) << 3)]; \
        short8 al_ = *(const short8*)&sA[rb_ + (((4 | fk3) ^ rx_) << 3)]; \
        S0; S1; \
        __builtin_amdgcn_s_barrier(); \
        asm volatile("s_waitcnt lgkmcnt(0)" ::: "memory"); \
        __builtin_amdgcn_sched_barrier(0); \
        __builtin_amdgcn_s_setprio(1); \
        _Pragma("unroll") \
        for (int n_ = 0; n_ < 4; ++n_) { \
            acc[i][n_] = MFMA_BF16(ah_, bh[n_], acc[i][n_]); \
            acc[i][n_] = MFMA_BF16(ah_, bl[n_], acc[i][n_]); \
            acc[i][n_] = MFMA_BF16(al_, bh[n_], acc[i][n_]); \
        } \
        __builtin_amdgcn_s_setprio(0); \
    } while (0)

    for (int s = 0; s < 32; ++s) {
        const short* sA = (const short*)(smem + (s % 3) * 49152);
        const short* sB = sA + 16384;
        short* dA = (short*)(smem + ((s + 2) % 3) * 49152);
        short* dB = dA + 16384;
        const bool pre = (s < 30);
        const int kbo = (s + 2) * 64;

        // B fragments for the whole K-step (read in phase 0)
        short8 bh[4], bl[4];
#pragma unroll
        for (int n = 0; n < 4; ++n) {
            int r = wc + n * 16 + fr;
            int rb = r * 64, rx = r & 7;
            bh[n] = *(const short8*)&sB[rb + ((fk3 ^ rx) << 3)];
            bl[n] = *(const short8*)&sB[rb + (((4 | fk3) ^ rx) << 3)];
        }
        PHASE(0,
              if (pre) GLOAD16(Aws + gA0 + kbo, dA + t * 8),
              if (pre) GLOAD16(Aws + gA0 + 131072 + kbo, dA + 4096 + t * 8));
        __builtin_amdgcn_s_barrier();
        PHASE(1,
              if (pre) GLOAD16(Aws + gA0 + 262144 + kbo, dA + 8192 + t * 8),
              if (pre) GLOAD16(Aws + gA0 + 393216 + kbo, dA + 12288 + t * 8));
        __builtin_amdgcn_s_barrier();
        PHASE(2,
              if (pre) GLOAD16(Bws + gB0 + kbo, dB + t * 8),
              if (pre) GLOAD16(Bws + gB0 + 131072 + kbo, dB + 4096 + t * 8));
        __builtin_amdgcn_s_barrier();
        PHASE(3, , );
        // counted wait once per K-step: next step's 6 (oldest) must land;
        // this step's 6 prefetch loads stay in flight across the barrier
        if (pre) asm volatile("s_waitcnt vmcnt(6)" ::: "memory");
        else     asm volatile("s_waitcnt vmcnt(0)" ::: "memory");
        __builtin_amdgcn_s_barrier();
    }
#undef PHASE
#undef STAGE

    // ---- epilogue: math in fragment layout, per-wave LDS slab -> coalesced ----
    const float cv = cptr[0];
    const float rcv = sqrtf(cv);
    const float inv_rc = 1.0f / rcv;
    const int fc = l & 15, fq = (l >> 4) * 4;

    float cxr[16];
#pragma unroll
    for (int i = 0; i < 4; ++i)
#pragma unroll
        for (int q = 0; q < 4; ++q)
            cxr[i * 4 + q] = cx2[row0 + wr + i * 16 + fq + q];

    float chf[4], shf[4], wff[4];
#pragma unroll
    for (int n = 0; n < 4; ++n) {
        const int col = col0 + wc + n * 16 + fc;
        float dr = 2.0f * rcv * bias[col];
        chf[n] = coshf(dr) * 2.0f * invn[col];   // folds 2*invn
        shf[n] = sinhf(dr);
        wff[n] = 2.0f * wg[col] * inv_rc;
    }

    // per-wave PRIVATE slab: 16 rows x 64 cols, stride 68 floats, 4.25 KB
    float* slab = (float*)(smem + w * 8192);
    const int rr = l >> 4;          // 0..3 (read-phase row group)
    const int rc16 = l & 15;        // 0..15 (read-phase col group)

#pragma unroll
    for (int i = 0; i < 4; ++i) {
#pragma unroll
        for (int n = 0; n < 4; ++n)
#pragma unroll
            for (int q = 0; q < 4; ++q) {
                float a = acc[i][n][q];
                float mlr = fmaf(a, chf[n], -(1.0f + cxr[i * 4 + q]) * shf[n]);
                float wv = wff[n] * fast_asinh(mlr);
                slab[(fq + q) * 68 + n * 16 + fc] = fast_sinh(rcv * wv) * inv_rc;
            }
        // slab is private to this wave: no cross-wave barrier needed
#pragma unroll
        for (int p = 0; p < 4; ++p) {
            float4 v4 = *(const float4*)&slab[(p * 4 + rr) * 68 + rc16 * 4];
            *(float4*)&Y[(size_t)(row0 + wr + i * 16 + p * 4 + rr) * DIM +
                         col0 + wc + rc16 * 4] = v4;
        }
    }
}

// ---- per-row finalize: denom + relu-in-tangent + logmap0 ----
__global__ void finalize(float* __restrict__ Y, const float* __restrict__ cptr) {
    int row = blockIdx.x;
    float4* rp = (float4*)(Y + (size_t)row * DIM);
    float4 v = rp[threadIdx.x];
    float s1 = v.x * v.x + v.y * v.y + v.z * v.z + v.w * v.w;
    float rx = fmaxf(v.x, 0.f), ryy = fmaxf(v.y, 0.f);
    float rz = fmaxf(v.z, 0.f), rw = fmaxf(v.w, 0.f);
    float s2 = rx * rx + ryy * ryy + rz * rz + rw * rw;
    s1 = waveReduceSum(s1);
    s2 = waveReduceSum(s2);
    __shared__ float red1[4], red2[4];
    int wid = threadIdx.x >> 6, lane = threadIdx.x & 63;
    if (lane == 0) { red1[wid] = s1; red2[wid] = s2; }
    __syncthreads();
    s1 = red1[0] + red1[1] + red1[2] + red1[3];
    s2 = red2[0] + red2[1] + red2[2] + red2[3];

    const float c = cptr[0];
    const float rc = sqrtf(c);
    float g = 1.0f / (1.0f + sqrtf(1.0f + c * s1));     // x = g*y
    float xn = sqrtf(fmaxf(g * g * s1, 1e-15f));
    float arg = fminf(rc * xn, 1.0f - 1e-7f);
    float f1 = atanhf(arg) / (rc * xn);                  // u = f1*x
    float fv = f1 * g;                                   // v = fv*relu(y)
    float vn = sqrtf(fmaxf(fv * fv * s2, 1e-15f));
    float f2 = tanhf(rc * vn) / (rc * vn);               // e = f2*v
    float en = sqrtf(fmaxf(f2 * f2 * fv * fv * s2, 1e-15f));
    float maxnorm = (1.0f - 1e-5f) / rc;
    float pf = (en > maxnorm) ? (maxnorm / en) : 1.0f;   // z = pf*e
    float zn = sqrtf(fmaxf(pf * pf * f2 * f2 * fv * fv * s2, 1e-15f));
    float arg2 = fminf(rc * zn, 1.0f - 1e-7f);
    float f3 = atanhf(arg2) / (rc * zn);                 // out = f3*z
    float F = f3 * pf * f2 * fv;

    rp[threadIdx.x] = make_float4(F * rx, F * ryy, F * rz, F * rw);
}

extern "C" void kernel_launch(void* const* d_in, const int* in_sizes, int n_in,
                              void* d_out, int out_size, void* d_ws, size_t ws_size,
                              hipStream_t stream) {
    const float* inputs   = (const float*)d_in[0];
    const float* weigh_v  = (const float*)d_in[1];
    const float* weight_g = (const float*)d_in[2];
    const float* bias     = (const float*)d_in[3];
    const float* cptr     = (const float*)d_in[4];
    float* Y = (float*)d_out;

    // workspace layout (assumes ws_size >= ~69 MB)
    char* ws = (char*)d_ws;
    short* Aws = (short*)ws;                                      // 64 MB
    short* Bws = (short*)(ws + (size_t)64 * 1024 * 1024);         // 4 MB
    float* invn    = (float*)(ws + (size_t)68 * 1024 * 1024);     // 4 KB
    float* cx2     = (float*)(ws + (size_t)68 * 1024 * 1024 + 65536);   // 64 KB
    float* colpart = (float*)(ws + (size_t)68 * 1024 * 1024 + 131072);  // 32 KB

    colnorm_partial<<<32, 256, 0, stream>>>(weigh_v, colpart);
    colnorm_final<<<4, 256, 0, stream>>>(colpart, invn);
    wsplit<<<256, 256, 0, stream>>>(weigh_v, Bws);
    rowprep_split<<<M_ROWS, 256, 0, stream>>>(inputs, cptr, Aws, cx2);

    gemm_mfma<<<512, 512, 0, stream>>>(Aws, Bws, cx2, invn,
                                       weight_g, bias, cptr, Y);

    finalize<<<M_ROWS, 256, 0, stream>>>(Y, cptr);
}

// Round 10
// 172.502 us; speedup vs baseline: 1.0843x; 1.0843x over previous
//
#include <hip/hip_runtime.h>
#include <hip/hip_bf16.h>
#include <math.h>

#define M_ROWS 16384
#define DIM 1024

typedef __attribute__((ext_vector_type(8))) short short8;
typedef __attribute__((ext_vector_type(4))) float f32x4;

#define MFMA_BF16(a, b, c) __builtin_amdgcn_mfma_f32_16x16x32_bf16(a, b, c, 0, 0, 0)

#define GLOAD16(gp, lp) __builtin_amdgcn_global_load_lds( \
    (const __attribute__((address_space(1))) unsigned int*)(gp), \
    (__attribute__((address_space(3))) unsigned int*)(lp), 16, 0, 0)

__device__ __forceinline__ short bf16_hi(float x) {
    return (short)__bfloat16_as_ushort(__float2bfloat16(x));
}
__device__ __forceinline__ float bf16_f(short s) {
    return __bfloat162float(__ushort_as_bfloat16((unsigned short)s));
}

__device__ __forceinline__ float fast_asinh(float x) {
    float ax = fabsf(x);
    float r = __logf(ax + sqrtf(fmaf(ax, ax, 1.0f)));
    return copysignf(r, x);
}
__device__ __forceinline__ float fast_sinh(float x) {
    float e = __expf(x), em = __expf(-x);
    return 0.5f * (e - em);
}

__device__ __forceinline__ float waveReduceSum(float v) {
#pragma unroll
    for (int off = 32; off > 0; off >>= 1) v += __shfl_down(v, off, 64);
    return v;
}

// ---- column norms of weigh_v (axis=0) ----
__global__ void colnorm_partial(const float* __restrict__ W, float* __restrict__ part) {
    int col = (blockIdx.x & 3) * 256 + threadIdx.x;
    int r0 = (blockIdx.x >> 2) * 128;
    float s = 0.f;
#pragma unroll 8
    for (int i = 0; i < 128; ++i) {
        float t = W[(size_t)(r0 + i) * DIM + col];
        s += t * t;
    }
    part[(size_t)(blockIdx.x >> 2) * DIM + col] = s;
}

__global__ void colnorm_final(const float* __restrict__ part, float* __restrict__ invn) {
    int col = blockIdx.x * 256 + threadIdx.x;
    float s = 0.f;
#pragma unroll
    for (int p = 0; p < 8; ++p) s += part[(size_t)p * DIM + col];
    float n = fminf(fmaxf(sqrtf(s), 1e-6f), 1e6f);
    invn[col] = 1.0f / n;
}

// ---- transpose + bf16 hi/lo split of weigh_v into interleaved layout ----
// Bws[n][kb][0..31]=hi shorts, [32..63]=lo shorts  (row stride 2048 shorts)
__global__ __launch_bounds__(256) void wsplit(const float* __restrict__ W,
                                              short* __restrict__ Bws) {
    __shared__ float tile[64][65];
    const int t = threadIdx.x;
    const int k0 = (blockIdx.x >> 4) * 64, n0 = (blockIdx.x & 15) * 64;
    const int rk = t >> 4;          // 0..15
    const int cn = (t & 15) * 4;    // 0..60
#pragma unroll
    for (int p = 0; p < 4; ++p) {
        float4 v = *(const float4*)&W[(size_t)(k0 + rk + p * 16) * DIM + n0 + cn];
        tile[rk + p * 16][cn + 0] = v.x;
        tile[rk + p * 16][cn + 1] = v.y;
        tile[rk + p * 16][cn + 2] = v.z;
        tile[rk + p * 16][cn + 3] = v.w;
    }
    __syncthreads();
    const int rn = t >> 4;
    const int ck = (t & 15) * 4;          // 0..60, 4 k within one 32-chunk
    const int kbl = (t & 15) >> 3;        // 0 or 1
    const int ko = (t & 7) * 4;           // ck & 31
#pragma unroll
    for (int p = 0; p < 4; ++p) {
        int n = rn + p * 16;
        union { short s[4]; uint2 u; } ph, pl;
#pragma unroll
        for (int e = 0; e < 4; ++e) {
            float a = tile[ck + e][n];
            short h = bf16_hi(a);
            ph.s[e] = h;
            pl.s[e] = bf16_hi(a - bf16_f(h));
        }
        size_t base = (size_t)(n0 + n) * 2048 + (size_t)(k0 >> 5) * 64 + kbl * 64;
        *(uint2*)&Bws[base + ko]      = ph.u;
        *(uint2*)&Bws[base + 32 + ko] = pl.u;
    }
}

// ---- per-row prep into interleaved layout: Aws[row][kb][hi32|lo32] ----
__global__ __launch_bounds__(256) void rowprep_split(
    const float* __restrict__ in, const float* __restrict__ cptr,
    short* __restrict__ Aws, float* __restrict__ cx2) {
    const int row = blockIdx.x, t = threadIdx.x;
    float4 v = ((const float4*)(in + (size_t)row * DIM))[t];
    float s = v.x * v.x + v.y * v.y + v.z * v.z + v.w * v.w;
    s = waveReduceSum(s);
    __shared__ float red[4];
    __shared__ float rsv_sh;
    int wid = t >> 6, lane = t & 63;
    if (lane == 0) red[wid] = s;
    __syncthreads();
    if (t == 0) {
        float stot = red[0] + red[1] + red[2] + red[3];
        float cc = cptr[0], rc = sqrtf(cc);
        float un = sqrtf(fmaxf(stot, 1e-15f));          // _safe_norm(u)
        float xs = tanhf(rc * un) / (rc * un);          // x = xs*u
        float xn = sqrtf(fmaxf(xs * xs * stot, 1e-15f));
        float mn = (1.0f - 1e-5f) / rc;
        float pf = (xn > mn) ? (mn / xn) : 1.0f;        // proj
        float rsv = rc * xs * pf;                       // rcx = rsv*u
        rsv_sh = rsv;
        cx2[row] = rsv * rsv * stot;
    }
    __syncthreads();
    float rsv = rsv_sh;
    float a[4] = {v.x * rsv, v.y * rsv, v.z * rsv, v.w * rsv};
    union { short s[4]; uint2 u; } ph, pl;
#pragma unroll
    for (int e = 0; e < 4; ++e) {
        short h = bf16_hi(a[e]);
        ph.s[e] = h;
        pl.s[e] = bf16_hi(a[e] - bf16_f(h));
    }
    const int kb = t >> 3;          // (t*4)>>5
    const int ko = (t & 7) * 4;
    size_t base = (size_t)row * 2048 + kb * 64;
    *(uint2*)&Aws[base + ko]      = ph.u;
    *(uint2*)&Aws[base + 32 + ko] = pl.u;
}

// ---- MFMA GEMM (bf16x3), 256x256 tile, 8 waves (2M x 4N, 128x64 each) ----
// m201 geometry: one kb-block (K=32, hi|lo 64 shorts/row) per K-step, 32
// steps, 2-buffer 128 KB LDS, 4 phases per K-step. Wave-ownership staging:
// each wave stages ONLY the A-half and B-half it consumes (4+4 gloads, 2
// per phase), so its vmcnt(0) at phase-3 end covers exactly its own batch
// (issued >=1 phase earlier -> near-free), and the phase-3 closing
// s_barrier is the cross-wave visibility point.
// LDS rows: [rows][8 slots of 16B] (slots 0-3 hi, 4-7 lo), slot ^= row&7.
__global__ __launch_bounds__(512, 2) void gemm_mfma(
    const short* __restrict__ Aws, const short* __restrict__ Bws,
    const float* __restrict__ cx2, const float* __restrict__ invn,
    const float* __restrict__ wg, const float* __restrict__ bias,
    const float* __restrict__ cptr, float* __restrict__ Y) {
    __shared__ char smem[131072];   // [A0 32K | B0 32K | A1 32K | B1 32K]

    // 256 blocks = 64 by x 4 bx; XCD-chunked swizzle (256 % 8 == 0, bijective)
    const int j = blockIdx.x;
    const int wgid = (j & 7) * 32 + (j >> 3);
    const int by = wgid >> 2, bx = wgid & 3;
    const int row0 = by * 256, col0 = bx * 256;

    const int t = threadIdx.x;              // 0..511
    const int l = t & 63, w = t >> 6;       // 8 waves
    const int wr = (w >> 2) * 128, wc = (w & 3) * 64;
    const int fr = l & 15, fk3 = l >> 4;

    // ---- wave-ownership staging geometry ----
    const int ha = w >> 2;                  // my A-half (rows ha*128..+127)
    const int qa = w & 3;                   // quarter within the A-half
    const int hb = (w >> 1) & 1;            // my B-half
    const int qb = (w & 1) | ((w >> 2) << 1);
    const int lrow = l >> 3;                // 0..7
    const int gslot = ((l & 7) ^ (lrow & 7)) * 8;   // pre-swizzled source slot
    // share: 32 rows (q*32 + g*8 + lrow), 4 gloads of 1 KB each
    const size_t gAr = (size_t)(row0 + ha * 128 + qa * 32 + lrow) * 2048 + gslot;
    const size_t gBr = (size_t)(col0 + hb * 128 + qb * 32 + lrow) * 2048 + gslot;
    const int dAbase = (ha * 128 + qa * 32) * 64 + l * 8;   // + g*512 shorts
    const int dBbase = (hb * 128 + qb * 32) * 64 + l * 8;

    f32x4 acc[8][4] = {};

    // prologue: stage batch 0 into buf 0 (each wave: its own 2 halves)
    {
        short* dA = (short*)smem;
        short* dB = (short*)(smem + 32768);
#pragma unroll
        for (int g = 0; g < 4; ++g) {
            GLOAD16(Aws + gAr + g * 16384, dA + dAbase + g * 512);
            GLOAD16(Bws + gBr + g * 16384, dB + dBbase + g * 512);
        }
        asm volatile("s_waitcnt vmcnt(0)" ::: "memory");
        __builtin_amdgcn_s_barrier();
    }

#define DSRA(ig, ah, al) { \
        int r_ = wr + (ig) * 16 + fr; \
        int rb_ = r_ * 64, rx_ = r_ & 7; \
        ah = *(const short8*)&sA[rb_ + ((fk3 ^ rx_) << 3)]; \
        al = *(const short8*)&sA[rb_ + (((4 | fk3) ^ rx_) << 3)]; }

#define MFMA12(ig, ah, al) \
        _Pragma("unroll") \
        for (int n_ = 0; n_ < 4; ++n_) { \
            acc[ig][n_] = MFMA_BF16(ah, bh[n_], acc[ig][n_]); \
            acc[ig][n_] = MFMA_BF16(ah, bl[n_], acc[ig][n_]); \
            acc[ig][n_] = MFMA_BF16(al, bh[n_], acc[ig][n_]); }

    // 32 K-steps: one kb-block (K=32) each  [round-9 bug: ran only 16]
    for (int s = 0; s < 32; ++s) {
        const int cur = s & 1;
        const short* sA = (const short*)(smem + cur * 65536);
        const short* sB = sA + 16384;
        short* dA = (short*)(smem + (cur ^ 1) * 65536);
        short* dB = dA + 16384;
        const bool pre = (s < 31);
        const size_t kbo = (size_t)(s + 1) * 64;

        short8 bh[4], bl[4];
#pragma unroll
        for (int p = 0; p < 4; ++p) {
            // ds_read this phase's A fragment pair (+ all B frags in phase 0)
            short8 ah0, al0, ah1, al1;
            DSRA(2 * p,     ah0, al0);
            DSRA(2 * p + 1, ah1, al1);
            if (p == 0) {
#pragma unroll
                for (int n = 0; n < 4; ++n) {
                    int r = wc + n * 16 + fr;
                    int rb = r * 64, rx = r & 7;
                    bh[n] = *(const short8*)&sB[rb + ((fk3 ^ rx) << 3)];
                    bl[n] = *(const short8*)&sB[rb + (((4 | fk3) ^ rx) << 3)];
                }
            }
            // stage 2 of my 8 owned gloads for step s+1
            if (pre) {
                if (p == 0) {
                    GLOAD16(Aws + gAr + kbo,         dA + dAbase);
                    GLOAD16(Aws + gAr + 16384 + kbo, dA + dAbase + 512);
                } else if (p == 1) {
                    GLOAD16(Aws + gAr + 32768 + kbo, dA + dAbase + 1024);
                    GLOAD16(Aws + gAr + 49152 + kbo, dA + dAbase + 1536);
                } else if (p == 2) {
                    GLOAD16(Bws + gBr + kbo,         dB + dBbase);
                    GLOAD16(Bws + gBr + 16384 + kbo, dB + dBbase + 512);
                } else {
                    GLOAD16(Bws + gBr + 32768 + kbo, dB + dBbase + 1024);
                    GLOAD16(Bws + gBr + 49152 + kbo, dB + dBbase + 1536);
                }
            }
            __builtin_amdgcn_s_barrier();
            asm volatile("s_waitcnt lgkmcnt(0)" ::: "memory");
            __builtin_amdgcn_s_setprio(1);
            MFMA12(2 * p,     ah0, al0);
            MFMA12(2 * p + 1, ah1, al1);
            __builtin_amdgcn_s_setprio(0);
            if (p == 3) {
                // own batch for s+1 fully issued >=1 phase ago -> near-free;
                // closing barrier is the cross-wave visibility point
                asm volatile("s_waitcnt vmcnt(0)" ::: "memory");
            }
            __builtin_amdgcn_s_barrier();
        }
    }
#undef DSRA
#undef MFMA12

    // ---- epilogue: math in fragment layout, per-wave LDS slab -> coalesced ----
    const float cv = cptr[0];
    const float rcv = sqrtf(cv);
    const float inv_rc = 1.0f / rcv;
    const int fc = l & 15, fq = (l >> 4) * 4;

    float chf[4], shf[4], wff[4];
#pragma unroll
    for (int n = 0; n < 4; ++n) {
        const int col = col0 + wc + n * 16 + fc;
        float dr = 2.0f * rcv * bias[col];
        chf[n] = coshf(dr) * 2.0f * invn[col];   // folds 2*invn
        shf[n] = sinhf(dr);
        wff[n] = 2.0f * wg[col] * inv_rc;
    }

    // per-wave PRIVATE slab: 16 rows x 64 cols, stride 68 floats, 4.25 KB
    float* slab = (float*)(smem + w * 8192);
    const int rr = l >> 4;          // 0..3 (read-phase row group)
    const int rc16 = l & 15;        // 0..15 (read-phase col group)

#pragma unroll
    for (int i = 0; i < 8; ++i) {
        float cxr[4];
#pragma unroll
        for (int q = 0; q < 4; ++q)
            cxr[q] = cx2[row0 + wr + i * 16 + fq + q];
#pragma unroll
        for (int n = 0; n < 4; ++n)
#pragma unroll
            for (int q = 0; q < 4; ++q) {
                float a = acc[i][n][q];
                float mlr = fmaf(a, chf[n], -(1.0f + cxr[q]) * shf[n]);
                float wv = wff[n] * fast_asinh(mlr);
                slab[(fq + q) * 68 + n * 16 + fc] = fast_sinh(rcv * wv) * inv_rc;
            }
        // slab is private to this wave: no cross-wave barrier needed
#pragma unroll
        for (int p = 0; p < 4; ++p) {
            float4 v4 = *(const float4*)&slab[(p * 4 + rr) * 68 + rc16 * 4];
            *(float4*)&Y[(size_t)(row0 + wr + i * 16 + p * 4 + rr) * DIM +
                         col0 + wc + rc16 * 4] = v4;
        }
    }
}

// ---- per-row finalize: denom + relu-in-tangent + logmap0 ----
__global__ void finalize(float* __restrict__ Y, const float* __restrict__ cptr) {
    int row = blockIdx.x;
    float4* rp = (float4*)(Y + (size_t)row * DIM);
    float4 v = rp[threadIdx.x];
    float s1 = v.x * v.x + v.y * v.y + v.z * v.z + v.w * v.w;
    float rx = fmaxf(v.x, 0.f), ryy = fmaxf(v.y, 0.f);
    float rz = fmaxf(v.z, 0.f), rw = fmaxf(v.w, 0.f);
    float s2 = rx * rx + ryy * ryy + rz * rz + rw * rw;
    s1 = waveReduceSum(s1);
    s2 = waveReduceSum(s2);
    __shared__ float red1[4], red2[4];
    int wid = threadIdx.x >> 6, lane = threadIdx.x & 63;
    if (lane == 0) { red1[wid] = s1; red2[wid] = s2; }
    __syncthreads();
    s1 = red1[0] + red1[1] + red1[2] + red1[3];
    s2 = red2[0] + red2[1] + red2[2] + red2[3];

    const float c = cptr[0];
    const float rc = sqrtf(c);
    float g = 1.0f / (1.0f + sqrtf(1.0f + c * s1));     // x = g*y
    float xn = sqrtf(fmaxf(g * g * s1, 1e-15f));
    float arg = fminf(rc * xn, 1.0f - 1e-7f);
    float f1 = atanhf(arg) / (rc * xn);                  // u = f1*x
    float fv = f1 * g;                                   // v = fv*relu(y)
    float vn = sqrtf(fmaxf(fv * fv * s2, 1e-15f));
    float f2 = tanhf(rc * vn) / (rc * vn);               // e = f2*v
    float en = sqrtf(fmaxf(f2 * f2 * fv * fv * s2, 1e-15f));
    float maxnorm = (1.0f - 1e-5f) / rc;
    float pf = (en > maxnorm) ? (maxnorm / en) : 1.0f;   // z = pf*e
    float zn = sqrtf(fmaxf(pf * pf * f2 * f2 * fv * fv * s2, 1e-15f));
    float arg2 = fminf(rc * zn, 1.0f - 1e-7f);
    float f3 = atanhf(arg2) / (rc * zn);                 // out = f3*z
    float F = f3 * pf * f2 * fv;

    rp[threadIdx.x] = make_float4(F * rx, F * ryy, F * rz, F * rw);
}

extern "C" void kernel_launch(void* const* d_in, const int* in_sizes, int n_in,
                              void* d_out, int out_size, void* d_ws, size_t ws_size,
                              hipStream_t stream) {
    const float* inputs   = (const float*)d_in[0];
    const float* weigh_v  = (const float*)d_in[1];
    const float* weight_g = (const float*)d_in[2];
    const float* bias     = (const float*)d_in[3];
    const float* cptr     = (const float*)d_in[4];
    float* Y = (float*)d_out;

    // workspace layout (assumes ws_size >= ~69 MB)
    char* ws = (char*)d_ws;
    short* Aws = (short*)ws;                                      // 64 MB
    short* Bws = (short*)(ws + (size_t)64 * 1024 * 1024);         // 4 MB
    float* invn    = (float*)(ws + (size_t)68 * 1024 * 1024);     // 4 KB
    float* cx2     = (float*)(ws + (size_t)68 * 1024 * 1024 + 65536);   // 64 KB
    float* colpart = (float*)(ws + (size_t)68 * 1024 * 1024 + 131072);  // 32 KB

    colnorm_partial<<<32, 256, 0, stream>>>(weigh_v, colpart);
    colnorm_final<<<4, 256, 0, stream>>>(colpart, invn);
    wsplit<<<256, 256, 0, stream>>>(weigh_v, Bws);
    rowprep_split<<<M_ROWS, 256, 0, stream>>>(inputs, cptr, Aws, cx2);

    gemm_mfma<<<256, 512, 0, stream>>>(Aws, Bws, cx2, invn,
                                       weight_g, bias, cptr, Y);

    finalize<<<M_ROWS, 256, 0, stream>>>(Y, cptr);
}

// Round 11
// 171.723 us; speedup vs baseline: 1.0892x; 1.0045x over previous
//
#include <hip/hip_runtime.h>
#include <hip/hip_bf16.h>
#include <math.h>

#define M_ROWS 16384
#define DIM 1024

typedef __attribute__((ext_vector_type(8))) short short8;
typedef __attribute__((ext_vector_type(4))) float f32x4;

#define MFMA_BF16(a, b, c) __builtin_amdgcn_mfma_f32_16x16x32_bf16(a, b, c, 0, 0, 0)

#define GLOAD16(gp, lp) __builtin_amdgcn_global_load_lds( \
    (const __attribute__((address_space(1))) unsigned int*)(gp), \
    (__attribute__((address_space(3))) unsigned int*)(lp), 16, 0, 0)

__device__ __forceinline__ short bf16_hi(float x) {
    return (short)__bfloat16_as_ushort(__float2bfloat16(x));
}
__device__ __forceinline__ float bf16_f(short s) {
    return __bfloat162float(__ushort_as_bfloat16((unsigned short)s));
}

__device__ __forceinline__ float fast_asinh(float x) {
    float ax = fabsf(x);
    float r = __logf(ax + sqrtf(fmaf(ax, ax, 1.0f)));
    return copysignf(r, x);
}
__device__ __forceinline__ float fast_sinh(float x) {
    float e = __expf(x), em = __expf(-x);
    return 0.5f * (e - em);
}

__device__ __forceinline__ float waveReduceSum(float v) {
#pragma unroll
    for (int off = 32; off > 0; off >>= 1) v += __shfl_down(v, off, 64);
    return v;
}

// ---- column norms of weigh_v (axis=0) ----
__global__ void colnorm_partial(const float* __restrict__ W, float* __restrict__ part) {
    int col = (blockIdx.x & 3) * 256 + threadIdx.x;
    int r0 = (blockIdx.x >> 2) * 128;
    float s = 0.f;
#pragma unroll 8
    for (int i = 0; i < 128; ++i) {
        float t = W[(size_t)(r0 + i) * DIM + col];
        s += t * t;
    }
    part[(size_t)(blockIdx.x >> 2) * DIM + col] = s;
}

__global__ void colnorm_final(const float* __restrict__ part, float* __restrict__ invn) {
    int col = blockIdx.x * 256 + threadIdx.x;
    float s = 0.f;
#pragma unroll
    for (int p = 0; p < 8; ++p) s += part[(size_t)p * DIM + col];
    float n = fminf(fmaxf(sqrtf(s), 1e-6f), 1e6f);
    invn[col] = 1.0f / n;
}

// ---- transpose + bf16 hi/lo split of weigh_v into interleaved layout ----
// Bws[n][kb][0..31]=hi shorts, [32..63]=lo shorts  (row stride 2048 shorts)
__global__ __launch_bounds__(256) void wsplit(const float* __restrict__ W,
                                              short* __restrict__ Bws) {
    __shared__ float tile[64][65];
    const int t = threadIdx.x;
    const int k0 = (blockIdx.x >> 4) * 64, n0 = (blockIdx.x & 15) * 64;
    const int rk = t >> 4;          // 0..15
    const int cn = (t & 15) * 4;    // 0..60
#pragma unroll
    for (int p = 0; p < 4; ++p) {
        float4 v = *(const float4*)&W[(size_t)(k0 + rk + p * 16) * DIM + n0 + cn];
        tile[rk + p * 16][cn + 0] = v.x;
        tile[rk + p * 16][cn + 1] = v.y;
        tile[rk + p * 16][cn + 2] = v.z;
        tile[rk + p * 16][cn + 3] = v.w;
    }
    __syncthreads();
    const int rn = t >> 4;
    const int ck = (t & 15) * 4;          // 0..60, 4 k within one 32-chunk
    const int kbl = (t & 15) >> 3;        // 0 or 1
    const int ko = (t & 7) * 4;           // ck & 31
#pragma unroll
    for (int p = 0; p < 4; ++p) {
        int n = rn + p * 16;
        union { short s[4]; uint2 u; } ph, pl;
#pragma unroll
        for (int e = 0; e < 4; ++e) {
            float a = tile[ck + e][n];
            short h = bf16_hi(a);
            ph.s[e] = h;
            pl.s[e] = bf16_hi(a - bf16_f(h));
        }
        size_t base = (size_t)(n0 + n) * 2048 + (size_t)(k0 >> 5) * 64 + kbl * 64;
        *(uint2*)&Bws[base + ko]      = ph.u;
        *(uint2*)&Bws[base + 32 + ko] = pl.u;
    }
}

// ---- per-row prep into interleaved layout: Aws[row][kb][hi32|lo32] ----
__global__ __launch_bounds__(256) void rowprep_split(
    const float* __restrict__ in, const float* __restrict__ cptr,
    short* __restrict__ Aws, float* __restrict__ cx2) {
    const int row = blockIdx.x, t = threadIdx.x;
    float4 v = ((const float4*)(in + (size_t)row * DIM))[t];
    float s = v.x * v.x + v.y * v.y + v.z * v.z + v.w * v.w;
    s = waveReduceSum(s);
    __shared__ float red[4];
    __shared__ float rsv_sh;
    int wid = t >> 6, lane = t & 63;
    if (lane == 0) red[wid] = s;
    __syncthreads();
    if (t == 0) {
        float stot = red[0] + red[1] + red[2] + red[3];
        float cc = cptr[0], rc = sqrtf(cc);
        float un = sqrtf(fmaxf(stot, 1e-15f));          // _safe_norm(u)
        float xs = tanhf(rc * un) / (rc * un);          // x = xs*u
        float xn = sqrtf(fmaxf(xs * xs * stot, 1e-15f));
        float mn = (1.0f - 1e-5f) / rc;
        float pf = (xn > mn) ? (mn / xn) : 1.0f;        // proj
        float rsv = rc * xs * pf;                       // rcx = rsv*u
        rsv_sh = rsv;
        cx2[row] = rsv * rsv * stot;
    }
    __syncthreads();
    float rsv = rsv_sh;
    float a[4] = {v.x * rsv, v.y * rsv, v.z * rsv, v.w * rsv};
    union { short s[4]; uint2 u; } ph, pl;
#pragma unroll
    for (int e = 0; e < 4; ++e) {
        short h = bf16_hi(a[e]);
        ph.s[e] = h;
        pl.s[e] = bf16_hi(a[e] - bf16_f(h));
    }
    const int kb = t >> 3;          // (t*4)>>5
    const int ko = (t & 7) * 4;
    size_t base = (size_t)row * 2048 + kb * 64;
    *(uint2*)&Aws[base + ko]      = ph.u;
    *(uint2*)&Aws[base + 32 + ko] = pl.u;
}

// ---- MFMA GEMM (bf16x3), 256x256 tile, 8 waves (2M x 4N, 128x64 each) ----
// Round-11 schedule: 4 phases per K-step, ONE barrier per phase (m201's
// per-K barrier density), one-phase ds_read-ahead (MFMA consumes registers
// read in the previous phase -> compiler's counted lgkm waits satisfied by
// distance), all 8 owned gloads issued at phase 0 (>=3 phases before the
// phase-3 vmcnt(0) drain). Wave-ownership staging as round 10.
// LDS rows: [rows][8 slots of 16B] (slots 0-3 hi, 4-7 lo), slot ^= row&7.
__global__ __launch_bounds__(512, 2) void gemm_mfma(
    const short* __restrict__ Aws, const short* __restrict__ Bws,
    const float* __restrict__ cx2, const float* __restrict__ invn,
    const float* __restrict__ wg, const float* __restrict__ bias,
    const float* __restrict__ cptr, float* __restrict__ Y) {
    __shared__ char smem[131072];   // [A0 32K | B0 32K | A1 32K | B1 32K]

    // 256 blocks = 64 by x 4 bx; XCD-chunked swizzle (256 % 8 == 0, bijective)
    const int j = blockIdx.x;
    const int wgid = (j & 7) * 32 + (j >> 3);
    const int by = wgid >> 2, bx = wgid & 3;
    const int row0 = by * 256, col0 = bx * 256;

    const int t = threadIdx.x;              // 0..511
    const int l = t & 63, w = t >> 6;       // 8 waves
    const int wr = (w >> 2) * 128, wc = (w & 3) * 64;
    const int fr = l & 15, fk3 = l >> 4;

    // ---- wave-ownership staging geometry ----
    const int ha = w >> 2;                  // my A-half (rows ha*128..+127)
    const int qa = w & 3;                   // quarter within the A-half
    const int hb = (w >> 1) & 1;            // my B-half
    const int qb = (w & 1) | ((w >> 2) << 1);
    const int lrow = l >> 3;                // 0..7
    const int gslot = ((l & 7) ^ (lrow & 7)) * 8;   // pre-swizzled source slot
    const size_t gAr = (size_t)(row0 + ha * 128 + qa * 32 + lrow) * 2048 + gslot;
    const size_t gBr = (size_t)(col0 + hb * 128 + qb * 32 + lrow) * 2048 + gslot;
    const int dAbase = (ha * 128 + qa * 32) * 64 + l * 8;   // + g*512 shorts
    const int dBbase = (hb * 128 + qb * 32) * 64 + l * 8;

    f32x4 acc[8][4] = {};

    // prologue: stage batch 0 into buf 0 (each wave: its own 2 halves)
    {
        short* dA = (short*)smem;
        short* dB = (short*)(smem + 32768);
#pragma unroll
        for (int g = 0; g < 4; ++g) {
            GLOAD16(Aws + gAr + g * 16384, dA + dAbase + g * 512);
            GLOAD16(Bws + gBr + g * 16384, dB + dBbase + g * 512);
        }
        asm volatile("s_waitcnt vmcnt(0)" ::: "memory");
    }

    // barrier + compiler memory fence (prevents hoisting LDS reads above
    // the publish point; no instruction cost)
#define BARF() do { __builtin_amdgcn_s_barrier(); \
                    asm volatile("" ::: "memory"); } while (0)

#define DSRA(ig, ah, al) { \
        int r_ = wr + (ig) * 16 + fr; \
        int rb_ = r_ * 64, rx_ = r_ & 7; \
        ah = *(const short8*)&sA[rb_ + ((fk3 ^ rx_) << 3)]; \
        al = *(const short8*)&sA[rb_ + (((4 | fk3) ^ rx_) << 3)]; }

#define MFMA12(ig, ah, al) \
        _Pragma("unroll") \
        for (int n_ = 0; n_ < 4; ++n_) { \
            acc[ig][n_] = MFMA_BF16(ah, bh[n_], acc[ig][n_]); \
            acc[ig][n_] = MFMA_BF16(ah, bl[n_], acc[ig][n_]); \
            acc[ig][n_] = MFMA_BF16(al, bh[n_], acc[ig][n_]); }

    for (int s = 0; s < 32; ++s) {
        const int cur = s & 1;
        const short* sA = (const short*)(smem + cur * 65536);
        const short* sB = sA + 16384;
        short* dA = (short*)(smem + (cur ^ 1) * 65536);
        short* dB = dA + 16384;
        const bool pre = (s < 31);
        const size_t kbo = (size_t)(s + 1) * 64;

        short8 bh[4], bl[4];
        short8 r0h, r0l, r1h, r1l, r2h, r2l, r3h, r3l;

        // ---- phase 0: publish point of buf[cur]; stage all 8 owned gloads;
        //      read g0,g1 (this phase) + B + g2,g3 (next phase); MFMA g0,g1
        BARF();
        if (pre) {
            GLOAD16(Aws + gAr + kbo,         dA + dAbase);
            GLOAD16(Aws + gAr + 16384 + kbo, dA + dAbase + 512);
            GLOAD16(Aws + gAr + 32768 + kbo, dA + dAbase + 1024);
            GLOAD16(Aws + gAr + 49152 + kbo, dA + dAbase + 1536);
            GLOAD16(Bws + gBr + kbo,         dB + dBbase);
            GLOAD16(Bws + gBr + 16384 + kbo, dB + dBbase + 512);
            GLOAD16(Bws + gBr + 32768 + kbo, dB + dBbase + 1024);
            GLOAD16(Bws + gBr + 49152 + kbo, dB + dBbase + 1536);
        }
        DSRA(0, r0h, r0l);
        DSRA(1, r1h, r1l);
#pragma unroll
        for (int n = 0; n < 4; ++n) {
            int r = wc + n * 16 + fr;
            int rb = r * 64, rx = r & 7;
            bh[n] = *(const short8*)&sB[rb + ((fk3 ^ rx) << 3)];
            bl[n] = *(const short8*)&sB[rb + (((4 | fk3) ^ rx) << 3)];
        }
        DSRA(2, r2h, r2l);
        DSRA(3, r3h, r3l);
        __builtin_amdgcn_s_setprio(1);
        MFMA12(0, r0h, r0l);
        MFMA12(1, r1h, r1l);
        __builtin_amdgcn_s_setprio(0);

        // ---- phase 1: read g4,g5; MFMA g2,g3 (read last phase, already landed)
        BARF();
        DSRA(4, r0h, r0l);
        DSRA(5, r1h, r1l);
        __builtin_amdgcn_s_setprio(1);
        MFMA12(2, r2h, r2l);
        MFMA12(3, r3h, r3l);
        __builtin_amdgcn_s_setprio(0);

        // ---- phase 2: read g6,g7; MFMA g4,g5
        BARF();
        DSRA(6, r2h, r2l);
        DSRA(7, r3h, r3l);
        __builtin_amdgcn_s_setprio(1);
        MFMA12(4, r0h, r0l);
        MFMA12(5, r1h, r1l);
        __builtin_amdgcn_s_setprio(0);

        // ---- phase 3: MFMA g6,g7; drain own gloads (issued at phase 0)
        BARF();
        __builtin_amdgcn_s_setprio(1);
        MFMA12(6, r2h, r2l);
        MFMA12(7, r3h, r3l);
        __builtin_amdgcn_s_setprio(0);
        asm volatile("s_waitcnt vmcnt(0)" ::: "memory");
    }
#undef DSRA
#undef MFMA12
#undef BARF

    // ---- epilogue: math in fragment layout, per-wave LDS slab -> coalesced ----
    // buf0 (slab region) is quiescent once all waves passed the last phase-0
    // barrier: step 31 touches only buf1, no staging -> no race with slabs.
    const float cv = cptr[0];
    const float rcv = sqrtf(cv);
    const float inv_rc = 1.0f / rcv;
    const int fc = l & 15, fq = (l >> 4) * 4;

    float chf[4], shf[4], wff[4];
#pragma unroll
    for (int n = 0; n < 4; ++n) {
        const int col = col0 + wc + n * 16 + fc;
        float dr = 2.0f * rcv * bias[col];
        chf[n] = coshf(dr) * 2.0f * invn[col];   // folds 2*invn
        shf[n] = sinhf(dr);
        wff[n] = 2.0f * wg[col] * inv_rc;
    }

    // per-wave PRIVATE slab: 16 rows x 64 cols, stride 68 floats, 4.25 KB
    float* slab = (float*)(smem + w * 8192);
    const int rr = l >> 4;          // 0..3 (read-phase row group)
    const int rc16 = l & 15;        // 0..15 (read-phase col group)

#pragma unroll
    for (int i = 0; i < 8; ++i) {
        float cxr[4];
#pragma unroll
        for (int q = 0; q < 4; ++q)
            cxr[q] = cx2[row0 + wr + i * 16 + fq + q];
#pragma unroll
        for (int n = 0; n < 4; ++n)
#pragma unroll
            for (int q = 0; q < 4; ++q) {
                float a = acc[i][n][q];
                float mlr = fmaf(a, chf[n], -(1.0f + cxr[q]) * shf[n]);
                float wv = wff[n] * fast_asinh(mlr);
                slab[(fq + q) * 68 + n * 16 + fc] = fast_sinh(rcv * wv) * inv_rc;
            }
        // slab is private to this wave: no cross-wave barrier needed
#pragma unroll
        for (int p = 0; p < 4; ++p) {
            float4 v4 = *(const float4*)&slab[(p * 4 + rr) * 68 + rc16 * 4];
            *(float4*)&Y[(size_t)(row0 + wr + i * 16 + p * 4 + rr) * DIM +
                         col0 + wc + rc16 * 4] = v4;
        }
    }
}

// ---- per-row finalize: denom + relu-in-tangent + logmap0 ----
__global__ void finalize(float* __restrict__ Y, const float* __restrict__ cptr) {
    int row = blockIdx.x;
    float4* rp = (float4*)(Y + (size_t)row * DIM);
    float4 v = rp[threadIdx.x];
    float s1 = v.x * v.x + v.y * v.y + v.z * v.z + v.w * v.w;
    float rx = fmaxf(v.x, 0.f), ryy = fmaxf(v.y, 0.f);
    float rz = fmaxf(v.z, 0.f), rw = fmaxf(v.w, 0.f);
    float s2 = rx * rx + ryy * ryy + rz * rz + rw * rw;
    s1 = waveReduceSum(s1);
    s2 = waveReduceSum(s2);
    __shared__ float red1[4], red2[4];
    int wid = threadIdx.x >> 6, lane = threadIdx.x & 63;
    if (lane == 0) { red1[wid] = s1; red2[wid] = s2; }
    __syncthreads();
    s1 = red1[0] + red1[1] + red1[2] + red1[3];
    s2 = red2[0] + red2[1] + red2[2] + red2[3];

    const float c = cptr[0];
    const float rc = sqrtf(c);
    float g = 1.0f / (1.0f + sqrtf(1.0f + c * s1));     // x = g*y
    float xn = sqrtf(fmaxf(g * g * s1, 1e-15f));
    float arg = fminf(rc * xn, 1.0f - 1e-7f);
    float f1 = atanhf(arg) / (rc * xn);                  // u = f1*x
    float fv = f1 * g;                                   // v = fv*relu(y)
    float vn = sqrtf(fmaxf(fv * fv * s2, 1e-15f));
    float f2 = tanhf(rc * vn) / (rc * vn);               // e = f2*v
    float en = sqrtf(fmaxf(f2 * f2 * fv * fv * s2, 1e-15f));
    float maxnorm = (1.0f - 1e-5f) / rc;
    float pf = (en > maxnorm) ? (maxnorm / en) : 1.0f;   // z = pf*e
    float zn = sqrtf(fmaxf(pf * pf * f2 * f2 * fv * fv * s2, 1e-15f));
    float arg2 = fminf(rc * zn, 1.0f - 1e-7f);
    float f3 = atanhf(arg2) / (rc * zn);                 // out = f3*z
    float F = f3 * pf * f2 * fv;

    rp[threadIdx.x] = make_float4(F * rx, F * ryy, F * rz, F * rw);
}

extern "C" void kernel_launch(void* const* d_in, const int* in_sizes, int n_in,
                              void* d_out, int out_size, void* d_ws, size_t ws_size,
                              hipStream_t stream) {
    const float* inputs   = (const float*)d_in[0];
    const float* weigh_v  = (const float*)d_in[1];
    const float* weight_g = (const float*)d_in[2];
    const float* bias     = (const float*)d_in[3];
    const float* cptr     = (const float*)d_in[4];
    float* Y = (float*)d_out;

    // workspace layout (assumes ws_size >= ~69 MB)
    char* ws = (char*)d_ws;
    short* Aws = (short*)ws;                                      // 64 MB
    short* Bws = (short*)(ws + (size_t)64 * 1024 * 1024);         // 4 MB
    float* invn    = (float*)(ws + (size_t)68 * 1024 * 1024);     // 4 KB
    float* cx2     = (float*)(ws + (size_t)68 * 1024 * 1024 + 65536);   // 64 KB
    float* colpart = (float*)(ws + (size_t)68 * 1024 * 1024 + 131072);  // 32 KB

    colnorm_partial<<<32, 256, 0, stream>>>(weigh_v, colpart);
    colnorm_final<<<4, 256, 0, stream>>>(colpart, invn);
    wsplit<<<256, 256, 0, stream>>>(weigh_v, Bws);
    rowprep_split<<<M_ROWS, 256, 0, stream>>>(inputs, cptr, Aws, cx2);

    gemm_mfma<<<256, 512, 0, stream>>>(Aws, Bws, cx2, invn,
                                       weight_g, bias, cptr, Y);

    finalize<<<M_ROWS, 256, 0, stream>>>(Y, cptr);
}

// Round 12
// 127.365 us; speedup vs baseline: 1.4685x; 1.3483x over previous
//
#include <hip/hip_runtime.h>
#include <hip/hip_bf16.h>
#include <math.h>

#define M_ROWS 16384
#define DIM 1024

typedef __attribute__((ext_vector_type(8))) short short8;
typedef __attribute__((ext_vector_type(4))) float f32x4;

#define MFMA_BF16(a, b, c) __builtin_amdgcn_mfma_f32_16x16x32_bf16(a, b, c, 0, 0, 0)

#define GLOAD16(gp, lp) __builtin_amdgcn_global_load_lds( \
    (const __attribute__((address_space(1))) unsigned int*)(gp), \
    (__attribute__((address_space(3))) unsigned int*)(lp), 16, 0, 0)

__device__ __forceinline__ short bf16_hi(float x) {
    return (short)__bfloat16_as_ushort(__float2bfloat16(x));
}

__device__ __forceinline__ float fast_asinh(float x) {
    float ax = fabsf(x);
    float r = __logf(ax + sqrtf(fmaf(ax, ax, 1.0f)));
    return copysignf(r, x);
}
__device__ __forceinline__ float fast_sinh(float x) {
    float e = __expf(x), em = __expf(-x);
    return 0.5f * (e - em);
}

__device__ __forceinline__ float waveReduceSum(float v) {
#pragma unroll
    for (int off = 32; off > 0; off >>= 1) v += __shfl_down(v, off, 64);
    return v;
}

// ---- column norms of weigh_v (axis=0) ----
__global__ void colnorm_partial(const float* __restrict__ W, float* __restrict__ part) {
    int col = (blockIdx.x & 3) * 256 + threadIdx.x;
    int r0 = (blockIdx.x >> 2) * 128;
    float s = 0.f;
#pragma unroll 8
    for (int i = 0; i < 128; ++i) {
        float t = W[(size_t)(r0 + i) * DIM + col];
        s += t * t;
    }
    part[(size_t)(blockIdx.x >> 2) * DIM + col] = s;
}

__global__ void colnorm_final(const float* __restrict__ part, float* __restrict__ invn) {
    int col = blockIdx.x * 256 + threadIdx.x;
    float s = 0.f;
#pragma unroll
    for (int p = 0; p < 8; ++p) s += part[(size_t)p * DIM + col];
    float n = fminf(fmaxf(sqrtf(s), 1e-6f), 1e6f);
    invn[col] = 1.0f / n;
}

// ---- transpose weigh_v to bf16: Bws[n][k] row-major ----
__global__ __launch_bounds__(256) void wtrans(const float* __restrict__ W,
                                              short* __restrict__ Bws) {
    __shared__ float tile[64][65];
    const int t = threadIdx.x;
    const int k0 = (blockIdx.x >> 4) * 64, n0 = (blockIdx.x & 15) * 64;
    const int rk = t >> 4;          // 0..15
    const int cn = (t & 15) * 4;    // 0..60
#pragma unroll
    for (int p = 0; p < 4; ++p) {
        float4 v = *(const float4*)&W[(size_t)(k0 + rk + p * 16) * DIM + n0 + cn];
        tile[rk + p * 16][cn + 0] = v.x;
        tile[rk + p * 16][cn + 1] = v.y;
        tile[rk + p * 16][cn + 2] = v.z;
        tile[rk + p * 16][cn + 3] = v.w;
    }
    __syncthreads();
    const int rn = t >> 4;
    const int ck = (t & 15) * 4;
#pragma unroll
    for (int p = 0; p < 4; ++p) {
        int n = rn + p * 16;
        union { short s[4]; uint2 u; } ph;
#pragma unroll
        for (int e = 0; e < 4; ++e) ph.s[e] = bf16_hi(tile[ck + e][n]);
        *(uint2*)&Bws[(size_t)(n0 + n) * DIM + k0 + ck] = ph.u;
    }
}

// ---- per-row prep: rowscale factor, cx2, bf16 cast: Aws[row][k] ----
__global__ __launch_bounds__(256) void rowprep_bf16(
    const float* __restrict__ in, const float* __restrict__ cptr,
    short* __restrict__ Aws, float* __restrict__ cx2) {
    const int row = blockIdx.x, t = threadIdx.x;
    float4 v = ((const float4*)(in + (size_t)row * DIM))[t];
    float s = v.x * v.x + v.y * v.y + v.z * v.z + v.w * v.w;
    s = waveReduceSum(s);
    __shared__ float red[4];
    __shared__ float rsv_sh;
    int wid = t >> 6, lane = t & 63;
    if (lane == 0) red[wid] = s;
    __syncthreads();
    if (t == 0) {
        float stot = red[0] + red[1] + red[2] + red[3];
        float cc = cptr[0], rc = sqrtf(cc);
        float un = sqrtf(fmaxf(stot, 1e-15f));          // _safe_norm(u)
        float xs = tanhf(rc * un) / (rc * un);          // x = xs*u
        float xn = sqrtf(fmaxf(xs * xs * stot, 1e-15f));
        float mn = (1.0f - 1e-5f) / rc;
        float pf = (xn > mn) ? (mn / xn) : 1.0f;        // proj
        float rsv = rc * xs * pf;                       // rcx = rsv*u
        rsv_sh = rsv;
        cx2[row] = rsv * rsv * stot;
    }
    __syncthreads();
    float rsv = rsv_sh;
    union { short s[4]; uint2 u; } ph;
    ph.s[0] = bf16_hi(v.x * rsv);
    ph.s[1] = bf16_hi(v.y * rsv);
    ph.s[2] = bf16_hi(v.z * rsv);
    ph.s[3] = bf16_hi(v.w * rsv);
    *(uint2*)&Aws[(size_t)row * DIM + t * 4] = ph.u;
}

// ---- MFMA GEMM (single-product bf16), 256x256 tile, 8 waves (2M x 4N) ----
// BK=64 per buffer (16 steps x 2 phases), 2-buffer 128 KB LDS.
// LDS rows: [256 rows][128 B] (8 slots of 16B), slot' = slot ^ ((row>>1)&7)
// -> for aligned bases, read-side swizzle reduces to slot ^ (fr>>1).
// Wave-owned staging: 8 x 1KB gloads/wave/step issued at P0, drained by own
// vmcnt(0) at P1-end; next P0 barrier is the cross-wave publish point.
__global__ __launch_bounds__(512, 2) void gemm_mfma(
    const short* __restrict__ Aws, const short* __restrict__ Bws,
    const float* __restrict__ cx2, const float* __restrict__ invn,
    const float* __restrict__ wg, const float* __restrict__ bias,
    const float* __restrict__ cptr, float* __restrict__ Y) {
    __shared__ char smem[131072];   // [A0 32K | B0 32K | A1 32K | B1 32K]

    // 256 blocks = 64 by x 4 bx; XCD-chunked swizzle (256 % 8 == 0, bijective)
    const int j = blockIdx.x;
    const int wgid = (j & 7) * 32 + (j >> 3);
    const int by = wgid >> 2, bx = wgid & 3;
    const int row0 = by * 256, col0 = bx * 256;

    const int t = threadIdx.x;              // 0..511
    const int l = t & 63, w = t >> 6;       // 8 waves
    const int wr = (w >> 2) * 128, wc = (w & 3) * 64;
    const int fr = l & 15, fk3 = l >> 4;

    // read-side swizzled slot offsets (shorts): kc0 slot=fk3, kc1 slot=4|fk3
    const int swl = fr >> 1;
    const int pk0 = (fk3 ^ swl) * 8;
    const int pk1 = ((4 | fk3) ^ swl) * 8;

    // ---- wave-ownership staging geometry (rows multiple of 32) ----
    const int arow0 = (w >> 2) * 128 + (w & 3) * 32;   // my 32 A-rows
    const int brow0 = (w & 3) * 64 + (w >> 2) * 32;    // my 32 B-rows
    const int lrow8 = l >> 3;                          // 0..7 (row within gload)
    // source slot pre-swizzle: (l&7) ^ (4*(g&1) + (l>>4))
    const int se = ((l & 7) ^ (l >> 4)) * 8;           // g even
    const int so = ((l & 7) ^ (4 | (l >> 4))) * 8;     // g odd
    const size_t gA_base = (size_t)(row0 + arow0 + lrow8) * DIM;
    const size_t gB_base = (size_t)(col0 + brow0 + lrow8) * DIM;
    const int dAoff = arow0 * 64 + l * 8;              // shorts (+ g*512)
    const int dBoff = brow0 * 64 + l * 8;

#define STAGE8(dAp, dBp, kb) do { \
        GLOAD16(Aws + gA_base +     0 + (kb) + se, (dAp) + dAoff);        \
        GLOAD16(Aws + gA_base +  8192 + (kb) + so, (dAp) + dAoff + 512);  \
        GLOAD16(Aws + gA_base + 16384 + (kb) + se, (dAp) + dAoff + 1024); \
        GLOAD16(Aws + gA_base + 24576 + (kb) + so, (dAp) + dAoff + 1536); \
        GLOAD16(Bws + gB_base +     0 + (kb) + se, (dBp) + dBoff);        \
        GLOAD16(Bws + gB_base +  8192 + (kb) + so, (dBp) + dBoff + 512);  \
        GLOAD16(Bws + gB_base + 16384 + (kb) + se, (dBp) + dBoff + 1024); \
        GLOAD16(Bws + gB_base + 24576 + (kb) + so, (dBp) + dBoff + 1536); \
    } while (0)

#define BARF() do { __builtin_amdgcn_s_barrier(); \
                    asm volatile("" ::: "memory"); } while (0)

    f32x4 acc[8][4] = {};

    // prologue: stage step 0 into buf 0
    {
        short* dA = (short*)smem;
        short* dB = (short*)(smem + 32768);
        STAGE8(dA, dB, 0);
        asm volatile("s_waitcnt vmcnt(0)" ::: "memory");
    }

    for (int s = 0; s < 16; ++s) {
        const int cur = s & 1;
        const short* sA = (const short*)(smem + cur * 65536);
        const short* sB = sA + 16384;
        short* dA = (short*)(smem + (cur ^ 1) * 65536);
        short* dB = dA + 16384;
        const bool pre = (s < 15);
        const size_t kb = (size_t)(s + 1) * 64;

        short8 af[8], b0[4], b1[4];

        // ---- phase 0: publish buf[cur]; stage next step; kc0 compute ----
        BARF();
        if (pre) STAGE8(dA, dB, kb);
#pragma unroll
        for (int n = 0; n < 4; ++n) {
            int rb = (wc + n * 16 + fr) * 64;
            b0[n] = *(const short8*)&sB[rb + pk0];
            b1[n] = *(const short8*)&sB[rb + pk1];
        }
#pragma unroll
        for (int ig = 0; ig < 8; ++ig)
            af[ig] = *(const short8*)&sA[(wr + ig * 16 + fr) * 64 + pk0];
        __builtin_amdgcn_s_setprio(1);
#pragma unroll
        for (int ig = 0; ig < 8; ++ig)
#pragma unroll
            for (int n = 0; n < 4; ++n)
                acc[ig][n] = MFMA_BF16(af[ig], b0[n], acc[ig][n]);
        __builtin_amdgcn_s_setprio(0);

        // ---- phase 1: kc1 compute; drain own gloads ----
        BARF();
#pragma unroll
        for (int ig = 0; ig < 8; ++ig)
            af[ig] = *(const short8*)&sA[(wr + ig * 16 + fr) * 64 + pk1];
        __builtin_amdgcn_s_setprio(1);
#pragma unroll
        for (int ig = 0; ig < 8; ++ig)
#pragma unroll
            for (int n = 0; n < 4; ++n)
                acc[ig][n] = MFMA_BF16(af[ig], b1[n], acc[ig][n]);
        __builtin_amdgcn_s_setprio(0);
        asm volatile("s_waitcnt vmcnt(0)" ::: "memory");
    }
#undef STAGE8
#undef BARF

    // ---- epilogue: math in fragment layout, per-wave LDS slab -> coalesced ----
    // Slab lives in buf0; final step (s=15) reads buf1 only and all buf0
    // activity completed before the step-15 phase-0 barrier -> no race.
    const float cv = cptr[0];
    const float rcv = sqrtf(cv);
    const float inv_rc = 1.0f / rcv;
    const int fc = l & 15, fq = (l >> 4) * 4;

    float chf[4], shf[4], wff[4];
#pragma unroll
    for (int n = 0; n < 4; ++n) {
        const int col = col0 + wc + n * 16 + fc;
        float dr = 2.0f * rcv * bias[col];
        chf[n] = coshf(dr) * 2.0f * invn[col];   // folds 2*invn
        shf[n] = sinhf(dr);
        wff[n] = 2.0f * wg[col] * inv_rc;
    }

    // per-wave PRIVATE slab: 16 rows x 64 cols, stride 68 floats, 4.25 KB
    float* slab = (float*)(smem + w * 8192);
    const int rr = l >> 4;          // 0..3 (read-phase row group)
    const int rc16 = l & 15;        // 0..15 (read-phase col group)

#pragma unroll
    for (int i = 0; i < 8; ++i) {
        float cxr[4];
#pragma unroll
        for (int q = 0; q < 4; ++q)
            cxr[q] = cx2[row0 + wr + i * 16 + fq + q];
#pragma unroll
        for (int n = 0; n < 4; ++n)
#pragma unroll
            for (int q = 0; q < 4; ++q) {
                float a = acc[i][n][q];
                float mlr = fmaf(a, chf[n], -(1.0f + cxr[q]) * shf[n]);
                float wv = wff[n] * fast_asinh(mlr);
                slab[(fq + q) * 68 + n * 16 + fc] = fast_sinh(rcv * wv) * inv_rc;
            }
#pragma unroll
        for (int p = 0; p < 4; ++p) {
            float4 v4 = *(const float4*)&slab[(p * 4 + rr) * 68 + rc16 * 4];
            *(float4*)&Y[(size_t)(row0 + wr + i * 16 + p * 4 + rr) * DIM +
                         col0 + wc + rc16 * 4] = v4;
        }
    }
}

// ---- per-row finalize: denom + relu-in-tangent + logmap0 ----
__global__ void finalize(float* __restrict__ Y, const float* __restrict__ cptr) {
    int row = blockIdx.x;
    float4* rp = (float4*)(Y + (size_t)row * DIM);
    float4 v = rp[threadIdx.x];
    float s1 = v.x * v.x + v.y * v.y + v.z * v.z + v.w * v.w;
    float rx = fmaxf(v.x, 0.f), ryy = fmaxf(v.y, 0.f);
    float rz = fmaxf(v.z, 0.f), rw = fmaxf(v.w, 0.f);
    float s2 = rx * rx + ryy * ryy + rz * rz + rw * rw;
    s1 = waveReduceSum(s1);
    s2 = waveReduceSum(s2);
    __shared__ float red1[4], red2[4];
    int wid = threadIdx.x >> 6, lane = threadIdx.x & 63;
    if (lane == 0) { red1[wid] = s1; red2[wid] = s2; }
    __syncthreads();
    s1 = red1[0] + red1[1] + red1[2] + red1[3];
    s2 = red2[0] + red2[1] + red2[2] + red2[3];

    const float c = cptr[0];
    const float rc = sqrtf(c);
    float g = 1.0f / (1.0f + sqrtf(1.0f + c * s1));     // x = g*y
    float xn = sqrtf(fmaxf(g * g * s1, 1e-15f));
    float arg = fminf(rc * xn, 1.0f - 1e-7f);
    float f1 = atanhf(arg) / (rc * xn);                  // u = f1*x
    float fv = f1 * g;                                   // v = fv*relu(y)
    float vn = sqrtf(fmaxf(fv * fv * s2, 1e-15f));
    float f2 = tanhf(rc * vn) / (rc * vn);               // e = f2*v
    float en = sqrtf(fmaxf(f2 * f2 * fv * fv * s2, 1e-15f));
    float maxnorm = (1.0f - 1e-5f) / rc;
    float pf = (en > maxnorm) ? (maxnorm / en) : 1.0f;   // z = pf*e
    float zn = sqrtf(fmaxf(pf * pf * f2 * f2 * fv * fv * s2, 1e-15f));
    float arg2 = fminf(rc * zn, 1.0f - 1e-7f);
    float f3 = atanhf(arg2) / (rc * zn);                 // out = f3*z
    float F = f3 * pf * f2 * fv;

    rp[threadIdx.x] = make_float4(F * rx, F * ryy, F * rz, F * rw);
}

extern "C" void kernel_launch(void* const* d_in, const int* in_sizes, int n_in,
                              void* d_out, int out_size, void* d_ws, size_t ws_size,
                              hipStream_t stream) {
    const float* inputs   = (const float*)d_in[0];
    const float* weigh_v  = (const float*)d_in[1];
    const float* weight_g = (const float*)d_in[2];
    const float* bias     = (const float*)d_in[3];
    const float* cptr     = (const float*)d_in[4];
    float* Y = (float*)d_out;

    // workspace layout (assumes ws_size >= ~35 MB)
    char* ws = (char*)d_ws;
    short* Aws = (short*)ws;                                      // 32 MB
    short* Bws = (short*)(ws + (size_t)32 * 1024 * 1024);         // 2 MB
    float* invn    = (float*)(ws + (size_t)34 * 1024 * 1024);     // 4 KB
    float* cx2     = (float*)(ws + (size_t)34 * 1024 * 1024 + 65536);   // 64 KB
    float* colpart = (float*)(ws + (size_t)34 * 1024 * 1024 + 131072);  // 32 KB

    colnorm_partial<<<32, 256, 0, stream>>>(weigh_v, colpart);
    colnorm_final<<<4, 256, 0, stream>>>(colpart, invn);
    wtrans<<<256, 256, 0, stream>>>(weigh_v, Bws);
    rowprep_bf16<<<M_ROWS, 256, 0, stream>>>(inputs, cptr, Aws, cx2);

    gemm_mfma<<<256, 512, 0, stream>>>(Aws, Bws, cx2, invn,
                                       weight_g, bias, cptr, Y);

    finalize<<<M_ROWS, 256, 0, stream>>>(Y, cptr);
}